// Round 4
// baseline (977.686 us; speedup 1.0000x reference)
//
#include <hip/hip_runtime.h>
#include <math.h>

#define N   50000
#define E   800000
#define F   128
#define DIM 128
#define NF  4
#define ND  32
#define NL  3
#define NC  10
#define G   256
#define NB  196    // ceil(N/256) scan blocks

__device__ __forceinline__ float sigm(float v) { return 1.0f / (1.0f + __expf(-v)); }

// vl[f][k] = sum_j lin0_W[f][k][j]*att_W[f][j] ; vr likewise with Wr; cc[f] = att_b + b.(Wl+Wr)
__global__ void prep_kernel(const float* __restrict__ lin0_W, const float* __restrict__ lin0_b,
                            const float* __restrict__ att_W, const float* __restrict__ att_b,
                            float* __restrict__ vl, float* __restrict__ vr, float* __restrict__ cc) {
    int t = blockIdx.x * blockDim.x + threadIdx.x;
    if (t < NF * F) {
        int f = t >> 7, k = t & 127;
        const float* W  = lin0_W + (size_t)f * F * DIM + (size_t)k * DIM;
        const float* wl = att_W + f * 2 * DIM;
        const float* wr = wl + DIM;
        float sl = 0.f, sr = 0.f;
        for (int j = 0; j < DIM; ++j) { sl += W[j] * wl[j]; sr += W[j] * wr[j]; }
        vl[t] = sl; vr[t] = sr;
    }
    if (t < NF) {
        const float* b  = lin0_b + t * DIM;
        const float* wl = att_W + t * 2 * DIM;
        const float* wr = wl + DIM;
        float s = att_b[t];
        for (int j = 0; j < DIM; ++j) s += b[j] * (wl[j] + wr[j]);
        cc[t] = s;
    }
}

// lane = node, wave = f. Weights are wave-uniform -> SGPR streamed.
__global__ __launch_bounds__(256) void encode_kernel(
        const float* __restrict__ x, const float* __restrict__ enc_W,
        const float* __restrict__ enc_b,
        const float* __restrict__ vl, const float* __restrict__ vr,
        float* __restrict__ out, float* __restrict__ alr) {
    int tid = threadIdx.x;
    int f = __builtin_amdgcn_readfirstlane(tid >> 6);
    int n = blockIdx.x * 64 + (tid & 63);
    int nc = n < N ? n : N - 1;
    const float* px  = x + (size_t)nc * F;
    const float* wf  = enc_W + (size_t)f * F * ND;
    const float* pvl = vl + f * F;
    const float* pvr = vr + f * F;
    const float* pb  = enc_b + f * ND;
    float acc[32];
    #pragma unroll
    for (int j = 0; j < 32; ++j) acc[j] = pb[j];
    float sl = 0.f, sr = 0.f;
    for (int k4 = 0; k4 < 32; ++k4) {
        float4 xv = *(const float4*)(px + k4 * 4);
        float xs[4] = {xv.x, xv.y, xv.z, xv.w};
        #pragma unroll
        for (int u = 0; u < 4; ++u) {
            int k = k4 * 4 + u;
            float xk = xs[u];
            const float* wrow = wf + k * 32;
            #pragma unroll
            for (int j = 0; j < 32; ++j) acc[j] = fmaf(xk, wrow[j], acc[j]);
            sl = fmaf(xk, pvl[k], sl);
            sr = fmaf(xk, pvr[k], sr);
        }
    }
    if (n < N) {
        float* po = out + (size_t)n * DIM + f * ND;
        #pragma unroll
        for (int q = 0; q < 8; ++q)
            *(float4*)(po + q * 4) = make_float4(acc[4*q], acc[4*q+1], acc[4*q+2], acc[4*q+3]);
        alr[(size_t)n * 8 + f]     = sl;
        alr[(size_t)n * 8 + 4 + f] = sr;
    }
}

__global__ void att_kernel(const int* __restrict__ ei, const float* __restrict__ alr,
                           const float* __restrict__ cc, float* __restrict__ atts) {
    int e = blockIdx.x * blockDim.x + threadIdx.x;
    if (e >= E) return;
    int s = ei[e];
    int d = ei[E + e];
    float4 al = *(const float4*)(alr + (size_t)s * 8);
    float4 ar = *(const float4*)(alr + (size_t)d * 8 + 4);
    atts[0 * (size_t)E + e] = sigm(6.f * (al.x + ar.x + cc[0]));
    atts[1 * (size_t)E + e] = sigm(6.f * (al.y + ar.y + cc[1]));
    atts[2 * (size_t)E + e] = sigm(6.f * (al.z + ar.z + cc[2]));
    atts[3 * (size_t)E + e] = sigm(6.f * (al.w + ar.w + cc[3]));
}

// ---------------- CSR build ----------------
__global__ void hist_kernel(const int* __restrict__ ei, int* __restrict__ deg) {
    int e = blockIdx.x * 256 + threadIdx.x;
    if (e < E) atomicAdd(&deg[ei[E + e]], 1);
}

__global__ void scan1_kernel(const int* __restrict__ deg, int* __restrict__ rowp,
                             int* __restrict__ bsum) {
    __shared__ int sh[256];
    int i = blockIdx.x * 256 + threadIdx.x;
    int v = (i < N) ? deg[i] : 0;
    sh[threadIdx.x] = v;
    __syncthreads();
    for (int off = 1; off < 256; off <<= 1) {
        int t = 0;
        if ((int)threadIdx.x >= off) t = sh[threadIdx.x - off];
        __syncthreads();
        sh[threadIdx.x] += t;
        __syncthreads();
    }
    if (i < N) rowp[i] = sh[threadIdx.x] - v;
    if (threadIdx.x == 255) bsum[blockIdx.x] = sh[255];
}

__global__ void scan2_kernel(int* __restrict__ bsum) {
    __shared__ int sh[256];
    int v = ((int)threadIdx.x < NB) ? bsum[threadIdx.x] : 0;
    sh[threadIdx.x] = v;
    __syncthreads();
    for (int off = 1; off < 256; off <<= 1) {
        int t = 0;
        if ((int)threadIdx.x >= off) t = sh[threadIdx.x - off];
        __syncthreads();
        sh[threadIdx.x] += t;
        __syncthreads();
    }
    if ((int)threadIdx.x < NB) bsum[threadIdx.x] = sh[threadIdx.x] - v;
}

__global__ void scan3_kernel(int* __restrict__ rowp, const int* __restrict__ bsum) {
    int i = blockIdx.x * 256 + threadIdx.x;
    if (i < N) rowp[i] += bsum[i >> 8];
}

__global__ void fill_kernel(const int* __restrict__ ei, const float* __restrict__ atts,
                            const int* __restrict__ rowp, int* __restrict__ cnt,
                            int* __restrict__ esrc, float* __restrict__ attp) {
    int e = blockIdx.x * 256 + threadIdx.x;
    if (e >= E) return;
    int d = ei[E + e];
    int slot = rowp[d] + atomicAdd(&cnt[d], 1);
    esrc[slot] = ei[e];
    attp[slot]                 = atts[e];
    attp[(size_t)E + slot]     = atts[(size_t)E + e];
    attp[2 * (size_t)E + slot] = atts[2 * (size_t)E + e];
    attp[3 * (size_t)E + slot] = atts[3 * (size_t)E + e];
}

// ---------------- gather (unroll x4 to batch the dependent load chain) ----------------
__global__ void gather_kernel(const int* __restrict__ esrc, const float* __restrict__ attp,
                              const int* __restrict__ rowp, const int* __restrict__ deg,
                              const float* __restrict__ out, float* __restrict__ agg) {
    int t = blockIdx.x * 256 + threadIdx.x;
    int n = t >> 5;
    if (n >= N) return;
    int c4 = t & 31;
    int f = c4 >> 3;
    int beg = rowp[n];
    int cnt = deg[n];
    const float* ap = attp + (size_t)f * E + beg;
    const int*   sp = esrc + beg;
    const float* ob = out + c4 * 4;
    float4 acc = make_float4(0.f, 0.f, 0.f, 0.f);
    int i = 0;
    for (; i + 4 <= cnt; i += 4) {
        int s0 = sp[i], s1 = sp[i + 1], s2 = sp[i + 2], s3 = sp[i + 3];
        float a0 = ap[i], a1 = ap[i + 1], a2 = ap[i + 2], a3 = ap[i + 3];
        float4 v0 = *(const float4*)(ob + (size_t)s0 * DIM);
        float4 v1 = *(const float4*)(ob + (size_t)s1 * DIM);
        float4 v2 = *(const float4*)(ob + (size_t)s2 * DIM);
        float4 v3 = *(const float4*)(ob + (size_t)s3 * DIM);
        acc.x += a0 * v0.x + a1 * v1.x + a2 * v2.x + a3 * v3.x;
        acc.y += a0 * v0.y + a1 * v1.y + a2 * v2.y + a3 * v3.y;
        acc.z += a0 * v0.z + a1 * v1.z + a2 * v2.z + a3 * v3.z;
        acc.w += a0 * v0.w + a1 * v1.w + a2 * v2.w + a3 * v3.w;
    }
    for (; i < cnt; ++i) {
        int s = sp[i];
        float a = ap[i];
        float4 v = *(const float4*)(ob + (size_t)s * DIM);
        acc.x += a * v.x; acc.y += a * v.y; acc.z += a * v.z; acc.w += a * v.w;
    }
    *(float4*)(agg + (size_t)n * DIM + c4 * 4) = acc;
}

// ---------------- conv + GRU: all-register, fully unrolled, zero LDS ----------------
// lane = node, wave = f group. Weights wave-uniform -> scalar loads.
// Two-pass GRU (j split 16+16) keeps peak VGPRs ~150.
__global__ __launch_bounds__(128, 3) void update_kernel(
        const float* __restrict__ agg, float* __restrict__ out,
        const float* __restrict__ Wrel, const float* __restrict__ brel,
        const float* __restrict__ Wroot,
        const float* __restrict__ Wih, const float* __restrict__ Whh,
        const float* __restrict__ bih, const float* __restrict__ bhh, int l) {
    int tid = threadIdx.x;
    int f = __builtin_amdgcn_readfirstlane((int)(blockIdx.y * 2) + (tid >> 6));
    int n = blockIdx.x * 64 + (tid & 63);
    int nc = n < N ? n : N - 1;
    const float* pa = agg + (size_t)nc * DIM + f * ND;
    const float* ph = out + (size_t)nc * DIM + f * ND;
    float a[32], h[32];
    #pragma unroll
    for (int q = 0; q < 8; ++q) {
        float4 va = *(const float4*)(pa + q * 4);
        float4 vh = *(const float4*)(ph + q * 4);
        a[4*q] = va.x; a[4*q+1] = va.y; a[4*q+2] = va.z; a[4*q+3] = va.w;
        h[4*q] = vh.x; h[4*q+1] = vh.y; h[4*q+2] = vh.z; h[4*q+3] = vh.w;
    }
    // --- conv: m = relu(a@Wrel + h@Wroot + brel) ---
    const float* wrel  = Wrel  + (size_t)(f * NL + l) * 1024;
    const float* wroot = Wroot + (size_t)(f * NL + l) * 1024;
    const float* pbr   = brel + (f * NL + l) * 32;
    float m[32];
    #pragma unroll
    for (int j = 0; j < 32; ++j) m[j] = pbr[j];
    #pragma unroll
    for (int k = 0; k < 32; ++k) {
        float ak = a[k], hk = h[k];
        const float* w1 = wrel + k * 32;
        const float* w2 = wroot + k * 32;
        #pragma unroll
        for (int j = 0; j < 32; ++j)
            m[j] = fmaf(ak, w1[j], fmaf(hk, w2[j], m[j]));
    }
    #pragma unroll
    for (int j = 0; j < 32; ++j) m[j] = fmaxf(m[j], 0.f);
    // --- GRU, two j-passes of 16 ---
    const float* wi  = Wih + (size_t)f * 3072;   // [j_out][k] rows of 32
    const float* wh  = Whh + (size_t)f * 3072;
    const float* pbi = bih + f * 96;
    const float* pbh = bhh + f * 96;
    #pragma unroll
    for (int half = 0; half < 2; ++half) {
        float rc[16], zc[16], nn2[16], hn[16];
        #pragma unroll
        for (int j = 0; j < 16; ++j) {
            int jj = half * 16 + j;
            rc[j]  = pbi[jj] + pbh[jj];
            zc[j]  = pbi[32 + jj] + pbh[32 + jj];
            nn2[j] = pbi[64 + jj];
            hn[j]  = pbh[64 + jj];
        }
        #pragma unroll
        for (int k = 0; k < 32; ++k) {
            float mk = m[k], hk = h[k];
            #pragma unroll
            for (int j = 0; j < 16; ++j) {
                int jj = half * 16 + j;
                rc[j]  = fmaf(mk, wi[jj * 32 + k],        fmaf(hk, wh[jj * 32 + k],        rc[j]));
                zc[j]  = fmaf(mk, wi[(32 + jj) * 32 + k], fmaf(hk, wh[(32 + jj) * 32 + k], zc[j]));
                nn2[j] = fmaf(mk, wi[(64 + jj) * 32 + k], nn2[j]);
                hn[j]  = fmaf(hk, wh[(64 + jj) * 32 + k], hn[j]);
            }
        }
        if (n < N) {
            float res[16];
            #pragma unroll
            for (int j = 0; j < 16; ++j) {
                float r  = sigm(rc[j]);
                float z  = sigm(zc[j]);
                float xx = nn2[j] + r * hn[j];
                float nn = 2.f * sigm(2.f * xx) - 1.f;   // tanh
                res[j] = (1.f - z) * nn + z * h[half * 16 + j];
            }
            float* po = out + (size_t)n * DIM + f * ND + half * 16;
            #pragma unroll
            for (int q = 0; q < 4; ++q)
                *(float4*)(po + q * 4) = make_float4(res[4*q], res[4*q+1], res[4*q+2], res[4*q+3]);
        }
    }
}

// ---------------- pooling ----------------
__global__ void ghist_kernel(const int* __restrict__ batch, int* __restrict__ gcnt) {
    int n = blockIdx.x * 256 + threadIdx.x;
    if (n < N) atomicAdd(&gcnt[batch[n]], 1);
}

__global__ void gscan_kernel(const int* __restrict__ gcnt, int* __restrict__ goff) {
    __shared__ int sh[256];
    int v = gcnt[threadIdx.x];
    sh[threadIdx.x] = v;
    __syncthreads();
    for (int off = 1; off < 256; off <<= 1) {
        int t = 0;
        if ((int)threadIdx.x >= off) t = sh[threadIdx.x - off];
        __syncthreads();
        sh[threadIdx.x] += t;
        __syncthreads();
    }
    goff[threadIdx.x] = sh[threadIdx.x] - v;
}

__global__ void pool_kernel(const float* __restrict__ st, const int* __restrict__ goff,
                            const int* __restrict__ gcnt, float* __restrict__ pooled,
                            float* __restrict__ outsout) {
    __shared__ float acc2[128];
    int g = blockIdx.x;
    int c = threadIdx.x & 127;
    int half = threadIdx.x >> 7;
    int beg = goff[g], cnt = gcnt[g];
    float acc = 0.f;
    for (int i = half; i < cnt; i += 2) acc += st[(size_t)(beg + i) * DIM + c];
    if (half == 1) acc2[c] = acc;
    __syncthreads();
    if (half == 0) {
        float tot = acc + acc2[c];
        float val = tot / fmaxf((float)cnt, 1.0f);
        pooled[g * DIM + c] = val;
        int f = c >> 5, d = c & 31;
        outsout[((size_t)f * G + g) * ND + d] = val;
    }
}

__global__ void mlp_kernel(const float* __restrict__ pooled,
                           const float* __restrict__ fc1_W, const float* __restrict__ fc1_b,
                           const float* __restrict__ fc2_W, const float* __restrict__ fc2_b,
                           float* __restrict__ pred) {
    __shared__ float row[DIM], hid[DIM];
    int g = blockIdx.x, c = threadIdx.x;
    row[c] = pooled[(size_t)g * DIM + c];
    __syncthreads();
    float acc = fc1_b[c];
    #pragma unroll 8
    for (int k = 0; k < DIM; ++k) acc += row[k] * fc1_W[k * DIM + c];
    hid[c] = fmaxf(acc, 0.f);
    __syncthreads();
    if (c < NC) {
        float p = fc2_b[c];
        for (int k = 0; k < DIM; ++k) p += hid[k] * fc2_W[k * NC + c];
        pred[(size_t)g * NC + c] = p;
    }
}

extern "C" void kernel_launch(void* const* d_in, const int* in_sizes, int n_in,
                              void* d_out, int out_size, void* d_ws, size_t ws_size,
                              hipStream_t stream) {
    const float* x         = (const float*)d_in[0];
    const int*   ei        = (const int*)  d_in[1];
    const int*   batch     = (const int*)  d_in[2];
    const float* lin0_W    = (const float*)d_in[3];
    const float* lin0_b    = (const float*)d_in[4];
    const float* att_W     = (const float*)d_in[5];
    const float* att_b     = (const float*)d_in[6];
    const float* enc_W     = (const float*)d_in[7];
    const float* enc_b     = (const float*)d_in[8];
    const float* conv_Wrel = (const float*)d_in[9];
    const float* conv_brel = (const float*)d_in[10];
    const float* conv_Wroot= (const float*)d_in[11];
    const float* gru_Wih   = (const float*)d_in[12];
    const float* gru_Whh   = (const float*)d_in[13];
    const float* gru_bih   = (const float*)d_in[14];
    const float* gru_bhh   = (const float*)d_in[15];
    const float* fc1_W     = (const float*)d_in[16];
    const float* fc1_b     = (const float*)d_in[17];
    const float* fc2_W     = (const float*)d_in[18];
    const float* fc2_b     = (const float*)d_in[19];

    float* outp    = (float*)d_out;
    float* pred    = outp;                       // G*NC
    float* atts    = outp + G * NC;              // NF*E
    float* outsout = atts + (size_t)NF * E;      // NF*G*ND

    float* fp     = (float*)d_ws;
    float* st     = fp;                   fp += (size_t)N * DIM;
    float* agg    = fp;                   fp += (size_t)N * DIM;
    float* alr    = fp;                   fp += (size_t)N * 8;
    float* vl     = fp;                   fp += NF * F;
    float* vr     = fp;                   fp += NF * F;
    float* cc     = fp;                   fp += 4;
    float* pooled = fp;                   fp += G * DIM;
    float* attp   = fp;                   fp += (size_t)NF * E;
    int* ip    = (int*)fp;
    int* deg   = ip;                      ip += N;
    int* cnt   = ip;                      ip += N;   // deg & cnt adjacent -> one memset
    int* rowp  = ip;                      ip += N;
    int* bsum  = ip;                      ip += 256;
    int* gcnt  = ip;                      ip += G;
    int* goff  = ip;                      ip += G;
    int* esrc  = ip;                      ip += E;

    hipMemsetAsync(deg, 0, (size_t)(2 * N) * sizeof(int), stream);
    hipMemsetAsync(gcnt, 0, (size_t)G * sizeof(int), stream);

    prep_kernel<<<2, 256, 0, stream>>>(lin0_W, lin0_b, att_W, att_b, vl, vr, cc);
    encode_kernel<<<(N + 63) / 64, 256, 0, stream>>>(x, enc_W, enc_b, vl, vr, st, alr);
    att_kernel<<<(E + 255) / 256, 256, 0, stream>>>(ei, alr, cc, atts);

    // CSR build (once; reused by all 3 layers)
    hist_kernel<<<(E + 255) / 256, 256, 0, stream>>>(ei, deg);
    scan1_kernel<<<NB, 256, 0, stream>>>(deg, rowp, bsum);
    scan2_kernel<<<1, 256, 0, stream>>>(bsum);
    scan3_kernel<<<NB, 256, 0, stream>>>(rowp, bsum);
    fill_kernel<<<(E + 255) / 256, 256, 0, stream>>>(ei, atts, rowp, cnt, esrc, attp);

    for (int l = 0; l < NL; ++l) {
        gather_kernel<<<(N * 32 + 255) / 256, 256, 0, stream>>>(esrc, attp, rowp, deg, st, agg);
        dim3 gupd((N + 63) / 64, 2);
        update_kernel<<<gupd, 128, 0, stream>>>(agg, st, conv_Wrel, conv_brel, conv_Wroot,
                                                gru_Wih, gru_Whh, gru_bih, gru_bhh, l);
    }

    ghist_kernel<<<(N + 255) / 256, 256, 0, stream>>>(batch, gcnt);
    gscan_kernel<<<1, 256, 0, stream>>>(gcnt, goff);
    pool_kernel<<<G, 256, 0, stream>>>(st, goff, gcnt, pooled, outsout);
    mlp_kernel<<<G, DIM, 0, stream>>>(pooled, fc1_W, fc1_b, fc2_W, fc2_b, pred);
}

// Round 5
// 819.200 us; speedup vs baseline: 1.1935x; 1.1935x over previous
//
#include <hip/hip_runtime.h>
#include <math.h>

#define N   50000
#define E   800000
#define F   128
#define DIM 128
#define NF  4
#define ND  32
#define NL  3
#define NC  10
#define G   256
#define NB  196    // ceil(N/256) scan blocks

__device__ __forceinline__ float sigm(float v) { return 1.0f / (1.0f + __expf(-v)); }

// vl[f][k] = sum_j lin0_W[f][k][j]*att_W[f][j] ; vr likewise with Wr; cc[f] = att_b + b.(Wl+Wr)
__global__ void prep_kernel(const float* __restrict__ lin0_W, const float* __restrict__ lin0_b,
                            const float* __restrict__ att_W, const float* __restrict__ att_b,
                            float* __restrict__ vl, float* __restrict__ vr, float* __restrict__ cc) {
    int t = blockIdx.x * blockDim.x + threadIdx.x;
    if (t < NF * F) {
        int f = t >> 7, k = t & 127;
        const float* W  = lin0_W + (size_t)f * F * DIM + (size_t)k * DIM;
        const float* wl = att_W + f * 2 * DIM;
        const float* wr = wl + DIM;
        float sl = 0.f, sr = 0.f;
        for (int j = 0; j < DIM; ++j) { sl += W[j] * wl[j]; sr += W[j] * wr[j]; }
        vl[t] = sl; vr[t] = sr;
    }
    if (t < NF) {
        const float* b  = lin0_b + t * DIM;
        const float* wl = att_W + t * 2 * DIM;
        const float* wr = wl + DIM;
        float s = att_b[t];
        for (int j = 0; j < DIM; ++j) s += b[j] * (wl[j] + wr[j]);
        cc[t] = s;
    }
}

// transpose GRU weights: wihT[f][k][j] = Wih[f][j][k]  (k-rows contiguous -> s_load_dwordx8)
__global__ void wtrans_kernel(const float* __restrict__ Wih, const float* __restrict__ Whh,
                              float* __restrict__ wihT, float* __restrict__ whhT) {
    int t = blockIdx.x * 256 + threadIdx.x;
    if (t >= NF * 3 * ND * ND) return;
    int f = t / 3072, rem = t % 3072;
    int k = rem / 96, j = rem % 96;
    wihT[t] = Wih[f * 3072 + j * 32 + k];
    whhT[t] = Whh[f * 3072 + j * 32 + k];
}

// lane = node, wave = f. Weights are wave-uniform -> SGPR streamed.
__global__ __launch_bounds__(256) void encode_kernel(
        const float* __restrict__ x, const float* __restrict__ enc_W,
        const float* __restrict__ enc_b,
        const float* __restrict__ vl, const float* __restrict__ vr,
        float* __restrict__ out, float* __restrict__ alr) {
    int tid = threadIdx.x;
    int f = __builtin_amdgcn_readfirstlane(tid >> 6);
    int n = blockIdx.x * 64 + (tid & 63);
    int nc = n < N ? n : N - 1;
    const float* px  = x + (size_t)nc * F;
    const float* wf  = enc_W + (size_t)f * F * ND;
    const float* pvl = vl + f * F;
    const float* pvr = vr + f * F;
    const float* pb  = enc_b + f * ND;
    float acc[32];
    #pragma unroll
    for (int j = 0; j < 32; ++j) acc[j] = pb[j];
    float sl = 0.f, sr = 0.f;
    for (int k4 = 0; k4 < 32; ++k4) {
        float4 xv = *(const float4*)(px + k4 * 4);
        float xs[4] = {xv.x, xv.y, xv.z, xv.w};
        #pragma unroll
        for (int u = 0; u < 4; ++u) {
            int k = k4 * 4 + u;
            float xk = xs[u];
            const float* wrow = wf + k * 32;
            #pragma unroll
            for (int j = 0; j < 32; ++j) acc[j] = fmaf(xk, wrow[j], acc[j]);
            sl = fmaf(xk, pvl[k], sl);
            sr = fmaf(xk, pvr[k], sr);
        }
    }
    if (n < N) {
        float* po = out + (size_t)n * DIM + f * ND;
        #pragma unroll
        for (int q = 0; q < 8; ++q)
            *(float4*)(po + q * 4) = make_float4(acc[4*q], acc[4*q+1], acc[4*q+2], acc[4*q+3]);
        alr[(size_t)n * 8 + f]     = sl;
        alr[(size_t)n * 8 + 4 + f] = sr;
    }
}

__global__ void att_kernel(const int* __restrict__ ei, const float* __restrict__ alr,
                           const float* __restrict__ cc, float* __restrict__ atts) {
    int e = blockIdx.x * blockDim.x + threadIdx.x;
    if (e >= E) return;
    int s = ei[e];
    int d = ei[E + e];
    float4 al = *(const float4*)(alr + (size_t)s * 8);
    float4 ar = *(const float4*)(alr + (size_t)d * 8 + 4);
    atts[0 * (size_t)E + e] = sigm(6.f * (al.x + ar.x + cc[0]));
    atts[1 * (size_t)E + e] = sigm(6.f * (al.y + ar.y + cc[1]));
    atts[2 * (size_t)E + e] = sigm(6.f * (al.z + ar.z + cc[2]));
    atts[3 * (size_t)E + e] = sigm(6.f * (al.w + ar.w + cc[3]));
}

// ---------------- CSR build ----------------
__global__ void hist_kernel(const int* __restrict__ ei, int* __restrict__ deg) {
    int e = blockIdx.x * 256 + threadIdx.x;
    if (e < E) atomicAdd(&deg[ei[E + e]], 1);
}

__global__ void scan1_kernel(const int* __restrict__ deg, int* __restrict__ rowp,
                             int* __restrict__ bsum) {
    __shared__ int sh[256];
    int i = blockIdx.x * 256 + threadIdx.x;
    int v = (i < N) ? deg[i] : 0;
    sh[threadIdx.x] = v;
    __syncthreads();
    for (int off = 1; off < 256; off <<= 1) {
        int t = 0;
        if ((int)threadIdx.x >= off) t = sh[threadIdx.x - off];
        __syncthreads();
        sh[threadIdx.x] += t;
        __syncthreads();
    }
    if (i < N) rowp[i] = sh[threadIdx.x] - v;
    if (threadIdx.x == 255) bsum[blockIdx.x] = sh[255];
}

__global__ void scan2_kernel(int* __restrict__ bsum) {
    __shared__ int sh[256];
    int v = ((int)threadIdx.x < NB) ? bsum[threadIdx.x] : 0;
    sh[threadIdx.x] = v;
    __syncthreads();
    for (int off = 1; off < 256; off <<= 1) {
        int t = 0;
        if ((int)threadIdx.x >= off) t = sh[threadIdx.x - off];
        __syncthreads();
        sh[threadIdx.x] += t;
        __syncthreads();
    }
    if ((int)threadIdx.x < NB) bsum[threadIdx.x] = sh[threadIdx.x] - v;
}

__global__ void scan3_kernel(int* __restrict__ rowp, const int* __restrict__ bsum) {
    int i = blockIdx.x * 256 + threadIdx.x;
    if (i < N) rowp[i] += bsum[i >> 8];
}

// attp4[slot] = float4(att0..att3) — one 16B record per edge for the gather
__global__ void fill_kernel(const int* __restrict__ ei, const float* __restrict__ atts,
                            const int* __restrict__ rowp, int* __restrict__ cnt,
                            int* __restrict__ esrc, float4* __restrict__ attp4) {
    int e = blockIdx.x * 256 + threadIdx.x;
    if (e >= E) return;
    int d = ei[E + e];
    int slot = rowp[d] + atomicAdd(&cnt[d], 1);
    esrc[slot] = ei[e];
    attp4[slot] = make_float4(atts[e], atts[(size_t)E + e],
                              atts[2 * (size_t)E + e], atts[3 * (size_t)E + e]);
}

// ---------------- gather: one wave per node ----------------
// lane = 2 channels (float2); esrc/rowp/deg wave-uniform -> scalar pipe;
// payload = one coalesced 512B dwordx2 load per edge per wave.
__global__ __launch_bounds__(256) void gather_kernel(
        const int* __restrict__ esrc, const float4* __restrict__ attp4,
        const int* __restrict__ rowp, const int* __restrict__ deg,
        const float* __restrict__ out, float* __restrict__ agg) {
    int gw = (blockIdx.x << 2) | ((int)threadIdx.x >> 6);
    int n = __builtin_amdgcn_readfirstlane(gw);       // wave-uniform node id
    int lane = threadIdx.x & 63;
    int f = lane >> 4;
    int beg = rowp[n];
    int cnt = deg[n];
    const int*   sp = esrc + beg;
    const float* ap = (const float*)(attp4 + beg) + f;   // component f of each record
    const float* ob = out + lane * 2;
    float ax = 0.f, ay = 0.f;
    int i = 0;
    for (; i + 4 <= cnt; i += 4) {
        int s0 = sp[i], s1 = sp[i + 1], s2 = sp[i + 2], s3 = sp[i + 3];
        float a0 = ap[4 * i], a1 = ap[4 * i + 4], a2 = ap[4 * i + 8], a3 = ap[4 * i + 12];
        float2 v0 = *(const float2*)(ob + (size_t)s0 * DIM);
        float2 v1 = *(const float2*)(ob + (size_t)s1 * DIM);
        float2 v2 = *(const float2*)(ob + (size_t)s2 * DIM);
        float2 v3 = *(const float2*)(ob + (size_t)s3 * DIM);
        ax += a0 * v0.x + a1 * v1.x + a2 * v2.x + a3 * v3.x;
        ay += a0 * v0.y + a1 * v1.y + a2 * v2.y + a3 * v3.y;
    }
    for (; i < cnt; ++i) {
        int s = sp[i];
        float a = ap[4 * i];
        float2 v = *(const float2*)(ob + (size_t)s * DIM);
        ax += a * v.x; ay += a * v.y;
    }
    *(float2*)(agg + (size_t)n * DIM + lane * 2) = make_float2(ax, ay);
}

// ---------------- conv + GRU: round-3 structure, 1-wave blocks, transposed LDS ----------------
// lane = node; f = blockIdx.y (uniform -> weights via s_load).
// LDS [k][lane] layout: conflict-free, 16KB/block -> 10 blocks/CU.
__global__ __launch_bounds__(64) void update_kernel(
        const float* __restrict__ agg, float* __restrict__ out,
        const float* __restrict__ Wrel, const float* __restrict__ brel,
        const float* __restrict__ Wroot,
        const float* __restrict__ wihT, const float* __restrict__ whhT,
        const float* __restrict__ bih, const float* __restrict__ bhh, int l) {
    __shared__ float sA[32 * 64];   // agg slice, then m (relu output)
    __shared__ float sH[32 * 64];   // h slice
    int lane = threadIdx.x;
    int f = blockIdx.y;
    int n = blockIdx.x * 64 + lane;
    int nc = n < N ? n : N - 1;
    const float* pa = agg + (size_t)nc * DIM + f * ND;
    const float* ph = out + (size_t)nc * DIM + f * ND;
    #pragma unroll
    for (int q = 0; q < 8; ++q) {
        float4 va = *(const float4*)(pa + q * 4);
        float4 vh = *(const float4*)(ph + q * 4);
        sA[(q * 4 + 0) * 64 + lane] = va.x; sA[(q * 4 + 1) * 64 + lane] = va.y;
        sA[(q * 4 + 2) * 64 + lane] = va.z; sA[(q * 4 + 3) * 64 + lane] = va.w;
        sH[(q * 4 + 0) * 64 + lane] = vh.x; sH[(q * 4 + 1) * 64 + lane] = vh.y;
        sH[(q * 4 + 2) * 64 + lane] = vh.z; sH[(q * 4 + 3) * 64 + lane] = vh.w;
    }
    __syncthreads();
    // --- conv: m = relu(a@Wrel + h@Wroot + brel) ---
    const float* wrel  = Wrel  + (size_t)(f * NL + l) * 1024;
    const float* wroot = Wroot + (size_t)(f * NL + l) * 1024;
    const float* pbr   = brel + (f * NL + l) * 32;
    {
        float m[32];
        #pragma unroll
        for (int j = 0; j < 32; ++j) m[j] = pbr[j];
        for (int k = 0; k < 32; ++k) {
            float ak = sA[k * 64 + lane], hk = sH[k * 64 + lane];
            const float* w1 = wrel + k * 32;
            const float* w2 = wroot + k * 32;
            #pragma unroll
            for (int j = 0; j < 32; ++j) m[j] = fmaf(ak, w1[j], fmaf(hk, w2[j], m[j]));
        }
        __syncthreads();
        #pragma unroll
        for (int j = 0; j < 32; ++j) sA[j * 64 + lane] = fmaxf(m[j], 0.f);  // sA now holds m
    }
    __syncthreads();
    // --- GRU (single pass, combined gi+gh accumulators) ---
    const float* wi  = wihT + (size_t)f * 3072;   // [k][96] contiguous rows
    const float* wh  = whhT + (size_t)f * 3072;
    const float* pbi = bih + f * 96;
    const float* pbh = bhh + f * 96;
    float racc[32], zacc[32], nacc[32], hnacc[32];
    #pragma unroll
    for (int j = 0; j < 32; ++j) {
        racc[j]  = pbi[j] + pbh[j];
        zacc[j]  = pbi[32 + j] + pbh[32 + j];
        nacc[j]  = pbi[64 + j];
        hnacc[j] = pbh[64 + j];
    }
    for (int k = 0; k < 32; ++k) {
        float mk = sA[k * 64 + lane], hk = sH[k * 64 + lane];
        const float* wik = wi + k * 96;
        const float* whk = wh + k * 96;
        #pragma unroll
        for (int j = 0; j < 32; ++j) {
            racc[j]  = fmaf(hk, whk[j],      fmaf(mk, wik[j],      racc[j]));
            zacc[j]  = fmaf(hk, whk[32 + j], fmaf(mk, wik[32 + j], zacc[j]));
            nacc[j]  = fmaf(mk, wik[64 + j], nacc[j]);
            hnacc[j] = fmaf(hk, whk[64 + j], hnacc[j]);
        }
    }
    if (n < N) {
        float res[32];
        #pragma unroll
        for (int j = 0; j < 32; ++j) {
            float r  = sigm(racc[j]);
            float z  = sigm(zacc[j]);
            float xx = nacc[j] + r * hnacc[j];
            float nn = 2.f * sigm(2.f * xx) - 1.f;   // tanh
            res[j] = (1.f - z) * nn + z * sH[j * 64 + lane];
        }
        float* po = out + (size_t)n * DIM + f * ND;
        #pragma unroll
        for (int q = 0; q < 8; ++q)
            *(float4*)(po + q * 4) = make_float4(res[4*q], res[4*q+1], res[4*q+2], res[4*q+3]);
    }
}

// ---------------- pooling ----------------
__global__ void ghist_kernel(const int* __restrict__ batch, int* __restrict__ gcnt) {
    int n = blockIdx.x * 256 + threadIdx.x;
    if (n < N) atomicAdd(&gcnt[batch[n]], 1);
}

__global__ void gscan_kernel(const int* __restrict__ gcnt, int* __restrict__ goff) {
    __shared__ int sh[256];
    int v = gcnt[threadIdx.x];
    sh[threadIdx.x] = v;
    __syncthreads();
    for (int off = 1; off < 256; off <<= 1) {
        int t = 0;
        if ((int)threadIdx.x >= off) t = sh[threadIdx.x - off];
        __syncthreads();
        sh[threadIdx.x] += t;
        __syncthreads();
    }
    goff[threadIdx.x] = sh[threadIdx.x] - v;
}

__global__ void pool_kernel(const float* __restrict__ st, const int* __restrict__ goff,
                            const int* __restrict__ gcnt, float* __restrict__ pooled,
                            float* __restrict__ outsout) {
    __shared__ float acc2[128];
    int g = blockIdx.x;
    int c = threadIdx.x & 127;
    int half = threadIdx.x >> 7;
    int beg = goff[g], cnt = gcnt[g];
    float acc = 0.f;
    for (int i = half; i < cnt; i += 2) acc += st[(size_t)(beg + i) * DIM + c];
    if (half == 1) acc2[c] = acc;
    __syncthreads();
    if (half == 0) {
        float tot = acc + acc2[c];
        float val = tot / fmaxf((float)cnt, 1.0f);
        pooled[g * DIM + c] = val;
        int f = c >> 5, d = c & 31;
        outsout[((size_t)f * G + g) * ND + d] = val;
    }
}

__global__ void mlp_kernel(const float* __restrict__ pooled,
                           const float* __restrict__ fc1_W, const float* __restrict__ fc1_b,
                           const float* __restrict__ fc2_W, const float* __restrict__ fc2_b,
                           float* __restrict__ pred) {
    __shared__ float row[DIM], hid[DIM];
    int g = blockIdx.x, c = threadIdx.x;
    row[c] = pooled[(size_t)g * DIM + c];
    __syncthreads();
    float acc = fc1_b[c];
    #pragma unroll 8
    for (int k = 0; k < DIM; ++k) acc += row[k] * fc1_W[k * DIM + c];
    hid[c] = fmaxf(acc, 0.f);
    __syncthreads();
    if (c < NC) {
        float p = fc2_b[c];
        for (int k = 0; k < DIM; ++k) p += hid[k] * fc2_W[k * NC + c];
        pred[(size_t)g * NC + c] = p;
    }
}

extern "C" void kernel_launch(void* const* d_in, const int* in_sizes, int n_in,
                              void* d_out, int out_size, void* d_ws, size_t ws_size,
                              hipStream_t stream) {
    const float* x         = (const float*)d_in[0];
    const int*   ei        = (const int*)  d_in[1];
    const int*   batch     = (const int*)  d_in[2];
    const float* lin0_W    = (const float*)d_in[3];
    const float* lin0_b    = (const float*)d_in[4];
    const float* att_W     = (const float*)d_in[5];
    const float* att_b     = (const float*)d_in[6];
    const float* enc_W     = (const float*)d_in[7];
    const float* enc_b     = (const float*)d_in[8];
    const float* conv_Wrel = (const float*)d_in[9];
    const float* conv_brel = (const float*)d_in[10];
    const float* conv_Wroot= (const float*)d_in[11];
    const float* gru_Wih   = (const float*)d_in[12];
    const float* gru_Whh   = (const float*)d_in[13];
    const float* gru_bih   = (const float*)d_in[14];
    const float* gru_bhh   = (const float*)d_in[15];
    const float* fc1_W     = (const float*)d_in[16];
    const float* fc1_b     = (const float*)d_in[17];
    const float* fc2_W     = (const float*)d_in[18];
    const float* fc2_b     = (const float*)d_in[19];

    float* outp    = (float*)d_out;
    float* pred    = outp;                       // G*NC
    float* atts    = outp + G * NC;              // NF*E
    float* outsout = atts + (size_t)NF * E;      // NF*G*ND

    float* fp     = (float*)d_ws;
    float* st     = fp;                   fp += (size_t)N * DIM;
    float* agg    = fp;                   fp += (size_t)N * DIM;
    float* alr    = fp;                   fp += (size_t)N * 8;
    float* vl     = fp;                   fp += NF * F;
    float* vr     = fp;                   fp += NF * F;
    float* cc     = fp;                   fp += 4;
    float* pooled = fp;                   fp += G * DIM;
    float* wihT   = fp;                   fp += NF * 3 * ND * ND;
    float* whhT   = fp;                   fp += NF * 3 * ND * ND;
    float4* attp4 = (float4*)fp;          fp += (size_t)NF * E;
    int* ip    = (int*)fp;
    int* deg   = ip;                      ip += N;
    int* cnt   = ip;                      ip += N;   // deg & cnt adjacent -> one memset
    int* rowp  = ip;                      ip += N;
    int* bsum  = ip;                      ip += 256;
    int* gcnt  = ip;                      ip += G;
    int* goff  = ip;                      ip += G;
    int* esrc  = ip;                      ip += E;

    hipMemsetAsync(deg, 0, (size_t)(2 * N) * sizeof(int), stream);
    hipMemsetAsync(gcnt, 0, (size_t)G * sizeof(int), stream);

    prep_kernel<<<2, 256, 0, stream>>>(lin0_W, lin0_b, att_W, att_b, vl, vr, cc);
    wtrans_kernel<<<(NF * 3 * ND * ND + 255) / 256, 256, 0, stream>>>(gru_Wih, gru_Whh, wihT, whhT);
    encode_kernel<<<(N + 63) / 64, 256, 0, stream>>>(x, enc_W, enc_b, vl, vr, st, alr);
    att_kernel<<<(E + 255) / 256, 256, 0, stream>>>(ei, alr, cc, atts);

    // CSR build (once; reused by all 3 layers)
    hist_kernel<<<(E + 255) / 256, 256, 0, stream>>>(ei, deg);
    scan1_kernel<<<NB, 256, 0, stream>>>(deg, rowp, bsum);
    scan2_kernel<<<1, 256, 0, stream>>>(bsum);
    scan3_kernel<<<NB, 256, 0, stream>>>(rowp, bsum);
    fill_kernel<<<(E + 255) / 256, 256, 0, stream>>>(ei, atts, rowp, cnt, esrc, attp4);

    for (int l = 0; l < NL; ++l) {
        gather_kernel<<<N / 4, 256, 0, stream>>>(esrc, attp4, rowp, deg, st, agg);
        dim3 gupd((N + 63) / 64, NF);
        update_kernel<<<gupd, 64, 0, stream>>>(agg, st, conv_Wrel, conv_brel, conv_Wroot,
                                               wihT, whhT, gru_bih, gru_bhh, l);
    }

    ghist_kernel<<<(N + 255) / 256, 256, 0, stream>>>(batch, gcnt);
    gscan_kernel<<<1, 256, 0, stream>>>(gcnt, goff);
    pool_kernel<<<G, 256, 0, stream>>>(st, goff, gcnt, pooled, outsout);
    mlp_kernel<<<G, DIM, 0, stream>>>(pooled, fc1_W, fc1_b, fc2_W, fc2_b, pred);
}

// Round 6
// 806.220 us; speedup vs baseline: 1.2127x; 1.0161x over previous
//
#include <hip/hip_runtime.h>
#include <math.h>

#define N   50000
#define E   800000
#define F   128
#define DIM 128
#define NF  4
#define ND  32
#define NL  3
#define NC  10
#define G   256
#define NB  196    // ceil(N/256) scan blocks

__device__ __forceinline__ float sigm(float v) { return 1.0f / (1.0f + __expf(-v)); }

// vl[f][k] = sum_j lin0_W[f][k][j]*att_W[f][j] ; vr likewise with Wr; cc[f] = att_b + b.(Wl+Wr)
__global__ void prep_kernel(const float* __restrict__ lin0_W, const float* __restrict__ lin0_b,
                            const float* __restrict__ att_W, const float* __restrict__ att_b,
                            float* __restrict__ vl, float* __restrict__ vr, float* __restrict__ cc) {
    int t = blockIdx.x * blockDim.x + threadIdx.x;
    if (t < NF * F) {
        int f = t >> 7, k = t & 127;
        const float* W  = lin0_W + (size_t)f * F * DIM + (size_t)k * DIM;
        const float* wl = att_W + f * 2 * DIM;
        const float* wr = wl + DIM;
        float sl = 0.f, sr = 0.f;
        for (int j = 0; j < DIM; ++j) { sl += W[j] * wl[j]; sr += W[j] * wr[j]; }
        vl[t] = sl; vr[t] = sr;
    }
    if (t < NF) {
        const float* b  = lin0_b + t * DIM;
        const float* wl = att_W + t * 2 * DIM;
        const float* wr = wl + DIM;
        float s = att_b[t];
        for (int j = 0; j < DIM; ++j) s += b[j] * (wl[j] + wr[j]);
        cc[t] = s;
    }
}

// lane = node, wave = f. Weights are wave-uniform -> SGPR streamed.
__global__ __launch_bounds__(256) void encode_kernel(
        const float* __restrict__ x, const float* __restrict__ enc_W,
        const float* __restrict__ enc_b,
        const float* __restrict__ vl, const float* __restrict__ vr,
        float* __restrict__ out, float* __restrict__ alr) {
    int tid = threadIdx.x;
    int f = __builtin_amdgcn_readfirstlane(tid >> 6);
    int n = blockIdx.x * 64 + (tid & 63);
    int nc = n < N ? n : N - 1;
    const float* px  = x + (size_t)nc * F;
    const float* wf  = enc_W + (size_t)f * F * ND;
    const float* pvl = vl + f * F;
    const float* pvr = vr + f * F;
    const float* pb  = enc_b + f * ND;
    float acc[32];
    #pragma unroll
    for (int j = 0; j < 32; ++j) acc[j] = pb[j];
    float sl = 0.f, sr = 0.f;
    for (int k4 = 0; k4 < 32; ++k4) {
        float4 xv = *(const float4*)(px + k4 * 4);
        float xs[4] = {xv.x, xv.y, xv.z, xv.w};
        #pragma unroll
        for (int u = 0; u < 4; ++u) {
            int k = k4 * 4 + u;
            float xk = xs[u];
            const float* wrow = wf + k * 32;
            #pragma unroll
            for (int j = 0; j < 32; ++j) acc[j] = fmaf(xk, wrow[j], acc[j]);
            sl = fmaf(xk, pvl[k], sl);
            sr = fmaf(xk, pvr[k], sr);
        }
    }
    if (n < N) {
        float* po = out + (size_t)n * DIM + f * ND;
        #pragma unroll
        for (int q = 0; q < 8; ++q)
            *(float4*)(po + q * 4) = make_float4(acc[4*q], acc[4*q+1], acc[4*q+2], acc[4*q+3]);
        alr[(size_t)n * 8 + f]     = sl;
        alr[(size_t)n * 8 + 4 + f] = sr;
    }
}

__global__ void att_kernel(const int* __restrict__ ei, const float* __restrict__ alr,
                           const float* __restrict__ cc, float* __restrict__ atts) {
    int e = blockIdx.x * blockDim.x + threadIdx.x;
    if (e >= E) return;
    int s = ei[e];
    int d = ei[E + e];
    float4 al = *(const float4*)(alr + (size_t)s * 8);
    float4 ar = *(const float4*)(alr + (size_t)d * 8 + 4);
    atts[0 * (size_t)E + e] = sigm(6.f * (al.x + ar.x + cc[0]));
    atts[1 * (size_t)E + e] = sigm(6.f * (al.y + ar.y + cc[1]));
    atts[2 * (size_t)E + e] = sigm(6.f * (al.z + ar.z + cc[2]));
    atts[3 * (size_t)E + e] = sigm(6.f * (al.w + ar.w + cc[3]));
}

// ---------------- CSR build ----------------
__global__ void hist_kernel(const int* __restrict__ ei, int* __restrict__ deg) {
    int e = blockIdx.x * 256 + threadIdx.x;
    if (e < E) atomicAdd(&deg[ei[E + e]], 1);
}

__global__ void scan1_kernel(const int* __restrict__ deg, int* __restrict__ rowp,
                             int* __restrict__ bsum) {
    __shared__ int sh[256];
    int i = blockIdx.x * 256 + threadIdx.x;
    int v = (i < N) ? deg[i] : 0;
    sh[threadIdx.x] = v;
    __syncthreads();
    for (int off = 1; off < 256; off <<= 1) {
        int t = 0;
        if ((int)threadIdx.x >= off) t = sh[threadIdx.x - off];
        __syncthreads();
        sh[threadIdx.x] += t;
        __syncthreads();
    }
    if (i < N) rowp[i] = sh[threadIdx.x] - v;
    if (threadIdx.x == 255) bsum[blockIdx.x] = sh[255];
}

__global__ void scan2_kernel(int* __restrict__ bsum) {
    __shared__ int sh[256];
    int v = ((int)threadIdx.x < NB) ? bsum[threadIdx.x] : 0;
    sh[threadIdx.x] = v;
    __syncthreads();
    for (int off = 1; off < 256; off <<= 1) {
        int t = 0;
        if ((int)threadIdx.x >= off) t = sh[threadIdx.x - off];
        __syncthreads();
        sh[threadIdx.x] += t;
        __syncthreads();
    }
    if ((int)threadIdx.x < NB) bsum[threadIdx.x] = sh[threadIdx.x] - v;
}

__global__ void scan3_kernel(int* __restrict__ rowp, const int* __restrict__ bsum) {
    int i = blockIdx.x * 256 + threadIdx.x;
    if (i < N) rowp[i] += bsum[i >> 8];
}

// attp4[slot] = float4(att0..att3) — one 16B record per edge for the gather
__global__ void fill_kernel(const int* __restrict__ ei, const float* __restrict__ atts,
                            const int* __restrict__ rowp, int* __restrict__ cnt,
                            int* __restrict__ esrc, float4* __restrict__ attp4) {
    int e = blockIdx.x * 256 + threadIdx.x;
    if (e >= E) return;
    int d = ei[E + e];
    int slot = rowp[d] + atomicAdd(&cnt[d], 1);
    esrc[slot] = ei[e];
    attp4[slot] = make_float4(atts[e], atts[(size_t)E + e],
                              atts[2 * (size_t)E + e], atts[3 * (size_t)E + e]);
}

// ---------------- gather: one wave per node ----------------
__global__ __launch_bounds__(256) void gather_kernel(
        const int* __restrict__ esrc, const float4* __restrict__ attp4,
        const int* __restrict__ rowp, const int* __restrict__ deg,
        const float* __restrict__ out, float* __restrict__ agg) {
    int gw = (blockIdx.x << 2) | ((int)threadIdx.x >> 6);
    int n = __builtin_amdgcn_readfirstlane(gw);       // wave-uniform node id
    int lane = threadIdx.x & 63;
    int f = lane >> 4;
    int beg = rowp[n];
    int cnt = deg[n];
    const int*   sp = esrc + beg;
    const float* ap = (const float*)(attp4 + beg) + f;   // component f of each record
    const float* ob = out + lane * 2;
    float ax = 0.f, ay = 0.f;
    int i = 0;
    for (; i + 4 <= cnt; i += 4) {
        int s0 = sp[i], s1 = sp[i + 1], s2 = sp[i + 2], s3 = sp[i + 3];
        float a0 = ap[4 * i], a1 = ap[4 * i + 4], a2 = ap[4 * i + 8], a3 = ap[4 * i + 12];
        float2 v0 = *(const float2*)(ob + (size_t)s0 * DIM);
        float2 v1 = *(const float2*)(ob + (size_t)s1 * DIM);
        float2 v2 = *(const float2*)(ob + (size_t)s2 * DIM);
        float2 v3 = *(const float2*)(ob + (size_t)s3 * DIM);
        ax += a0 * v0.x + a1 * v1.x + a2 * v2.x + a3 * v3.x;
        ay += a0 * v0.y + a1 * v1.y + a2 * v2.y + a3 * v3.y;
    }
    for (; i < cnt; ++i) {
        int s = sp[i];
        float a = ap[4 * i];
        float2 v = *(const float2*)(ob + (size_t)s * DIM);
        ax += a * v.x; ay += a * v.y;
    }
    *(float2*)(agg + (size_t)n * DIM + lane * 2) = make_float2(ax, ay);
}

// ---------------- conv + GRU: lane = output column j, nodes streamed ----------------
// Weights live in VGPRs (loaded once per block); activations broadcast from LDS.
// 1 wave/block; half-wave = one node; 32 node-steps per phase.
__global__ __launch_bounds__(64, 2) void update_kernel(
        const float* __restrict__ agg, float* __restrict__ out,
        const float* __restrict__ Wrel, const float* __restrict__ brel,
        const float* __restrict__ Wroot,
        const float* __restrict__ Wih, const float* __restrict__ Whh,
        const float* __restrict__ bih, const float* __restrict__ bhh, int l) {
    __shared__ float sA[64 * 32];   // [node][k] agg, later m
    __shared__ float sH[64 * 32];   // [node][k] h
    int lane = threadIdx.x;
    int f = blockIdx.y;
    int half = lane >> 5;
    int j = lane & 31;
    int node0 = blockIdx.x * 64;
    // stage agg/out rows for 64 nodes (clamped)
    for (int i4 = lane; i4 < 512; i4 += 64) {        // 512 float4 = 64 nodes x 32 ch
        int node = i4 >> 3, k4 = i4 & 7;
        int n = node0 + node; int nc = n < N ? n : N - 1;
        *(float4*)&sA[node * 32 + k4 * 4] = *(const float4*)(agg + (size_t)nc * DIM + f * ND + k4 * 4);
        *(float4*)&sH[node * 32 + k4 * 4] = *(const float4*)(out + (size_t)nc * DIM + f * ND + k4 * 4);
    }
    // conv weights: lane j holds column j of Wrel/Wroot
    const float* wrelg  = Wrel  + (size_t)(f * NL + l) * 1024;
    const float* wrootg = Wroot + (size_t)(f * NL + l) * 1024;
    float wr[32], wo[32];
    #pragma unroll
    for (int k = 0; k < 32; ++k) { wr[k] = wrelg[k * 32 + j]; wo[k] = wrootg[k * 32 + j]; }
    float br = brel[(f * NL + l) * 32 + j];
    __syncthreads();
    // conv: m = relu(a@Wrel + h@Wroot + brel); m overwrites sA
    for (int step = 0; step < 32; ++step) {
        int node = step * 2 + half;
        float a[32], h[32];
        #pragma unroll
        for (int q = 0; q < 8; ++q) {
            *(float4*)&a[q * 4] = *(const float4*)&sA[node * 32 + q * 4];
            *(float4*)&h[q * 4] = *(const float4*)&sH[node * 32 + q * 4];
        }
        float acc = br;
        #pragma unroll
        for (int k = 0; k < 32; ++k) acc = fmaf(a[k], wr[k], fmaf(h[k], wo[k], acc));
        sA[node * 32 + j] = fmaxf(acc, 0.f);      // safe: this step already read node's row
    }
    __syncthreads();
    // GRU weights: lane j holds rows j, 32+j, 64+j of Wih/Whh (original layout, contiguous)
    const float* wihg = Wih + (size_t)f * 3072;
    const float* whhg = Whh + (size_t)f * 3072;
    float wir[32], wiz[32], win[32], whr[32], whz[32], whn[32];
    #pragma unroll
    for (int q = 0; q < 8; ++q) {
        *(float4*)&wir[q * 4] = *(const float4*)&wihg[(j)      * 32 + q * 4];
        *(float4*)&wiz[q * 4] = *(const float4*)&wihg[(32 + j) * 32 + q * 4];
        *(float4*)&win[q * 4] = *(const float4*)&wihg[(64 + j) * 32 + q * 4];
        *(float4*)&whr[q * 4] = *(const float4*)&whhg[(j)      * 32 + q * 4];
        *(float4*)&whz[q * 4] = *(const float4*)&whhg[(32 + j) * 32 + q * 4];
        *(float4*)&whn[q * 4] = *(const float4*)&whhg[(64 + j) * 32 + q * 4];
    }
    float bi_r = bih[f * 96 + j] + bhh[f * 96 + j];
    float bi_z = bih[f * 96 + 32 + j] + bhh[f * 96 + 32 + j];
    float bi_n = bih[f * 96 + 64 + j];
    float bh_n = bhh[f * 96 + 64 + j];
    for (int step = 0; step < 32; ++step) {
        int node = step * 2 + half;
        int n = node0 + node;
        float racc = bi_r, zacc = bi_z, nacc = bi_n, hnacc = bh_n;
        #pragma unroll
        for (int c = 0; c < 2; ++c) {               // k chunks of 16 (reg pressure)
            float mv[16], hv[16];
            #pragma unroll
            for (int q = 0; q < 4; ++q) {
                *(float4*)&mv[q * 4] = *(const float4*)&sA[node * 32 + c * 16 + q * 4];
                *(float4*)&hv[q * 4] = *(const float4*)&sH[node * 32 + c * 16 + q * 4];
            }
            #pragma unroll
            for (int k = 0; k < 16; ++k) {
                int kk = c * 16 + k;
                racc  = fmaf(mv[k], wir[kk], fmaf(hv[k], whr[kk], racc));
                zacc  = fmaf(mv[k], wiz[kk], fmaf(hv[k], whz[kk], zacc));
                nacc  = fmaf(mv[k], win[kk], nacc);
                hnacc = fmaf(hv[k], whn[kk], hnacc);
            }
        }
        float r  = sigm(racc);
        float z  = sigm(zacc);
        float nn = 2.f * sigm(2.f * (nacc + r * hnacc)) - 1.f;   // tanh
        float hj = sH[node * 32 + j];
        float res = (1.f - z) * nn + z * hj;
        if (n < N) out[(size_t)n * DIM + f * ND + j] = res;
    }
}

// ---------------- pooling ----------------
__global__ void ghist_kernel(const int* __restrict__ batch, int* __restrict__ gcnt) {
    int n = blockIdx.x * 256 + threadIdx.x;
    if (n < N) atomicAdd(&gcnt[batch[n]], 1);
}

__global__ void gscan_kernel(const int* __restrict__ gcnt, int* __restrict__ goff) {
    __shared__ int sh[256];
    int v = gcnt[threadIdx.x];
    sh[threadIdx.x] = v;
    __syncthreads();
    for (int off = 1; off < 256; off <<= 1) {
        int t = 0;
        if ((int)threadIdx.x >= off) t = sh[threadIdx.x - off];
        __syncthreads();
        sh[threadIdx.x] += t;
        __syncthreads();
    }
    goff[threadIdx.x] = sh[threadIdx.x] - v;
}

__global__ void pool_kernel(const float* __restrict__ st, const int* __restrict__ goff,
                            const int* __restrict__ gcnt, float* __restrict__ pooled,
                            float* __restrict__ outsout) {
    __shared__ float acc2[128];
    int g = blockIdx.x;
    int c = threadIdx.x & 127;
    int half = threadIdx.x >> 7;
    int beg = goff[g], cnt = gcnt[g];
    float acc = 0.f;
    for (int i = half; i < cnt; i += 2) acc += st[(size_t)(beg + i) * DIM + c];
    if (half == 1) acc2[c] = acc;
    __syncthreads();
    if (half == 0) {
        float tot = acc + acc2[c];
        float val = tot / fmaxf((float)cnt, 1.0f);
        pooled[g * DIM + c] = val;
        int f = c >> 5, d = c & 31;
        outsout[((size_t)f * G + g) * ND + d] = val;
    }
}

__global__ void mlp_kernel(const float* __restrict__ pooled,
                           const float* __restrict__ fc1_W, const float* __restrict__ fc1_b,
                           const float* __restrict__ fc2_W, const float* __restrict__ fc2_b,
                           float* __restrict__ pred) {
    __shared__ float row[DIM], hid[DIM];
    int g = blockIdx.x, c = threadIdx.x;
    row[c] = pooled[(size_t)g * DIM + c];
    __syncthreads();
    float acc = fc1_b[c];
    #pragma unroll 8
    for (int k = 0; k < DIM; ++k) acc += row[k] * fc1_W[k * DIM + c];
    hid[c] = fmaxf(acc, 0.f);
    __syncthreads();
    if (c < NC) {
        float p = fc2_b[c];
        for (int k = 0; k < DIM; ++k) p += hid[k] * fc2_W[k * NC + c];
        pred[(size_t)g * NC + c] = p;
    }
}

extern "C" void kernel_launch(void* const* d_in, const int* in_sizes, int n_in,
                              void* d_out, int out_size, void* d_ws, size_t ws_size,
                              hipStream_t stream) {
    const float* x         = (const float*)d_in[0];
    const int*   ei        = (const int*)  d_in[1];
    const int*   batch     = (const int*)  d_in[2];
    const float* lin0_W    = (const float*)d_in[3];
    const float* lin0_b    = (const float*)d_in[4];
    const float* att_W     = (const float*)d_in[5];
    const float* att_b     = (const float*)d_in[6];
    const float* enc_W     = (const float*)d_in[7];
    const float* enc_b     = (const float*)d_in[8];
    const float* conv_Wrel = (const float*)d_in[9];
    const float* conv_brel = (const float*)d_in[10];
    const float* conv_Wroot= (const float*)d_in[11];
    const float* gru_Wih   = (const float*)d_in[12];
    const float* gru_Whh   = (const float*)d_in[13];
    const float* gru_bih   = (const float*)d_in[14];
    const float* gru_bhh   = (const float*)d_in[15];
    const float* fc1_W     = (const float*)d_in[16];
    const float* fc1_b     = (const float*)d_in[17];
    const float* fc2_W     = (const float*)d_in[18];
    const float* fc2_b     = (const float*)d_in[19];

    float* outp    = (float*)d_out;
    float* pred    = outp;                       // G*NC
    float* atts    = outp + G * NC;              // NF*E
    float* outsout = atts + (size_t)NF * E;      // NF*G*ND

    float* fp     = (float*)d_ws;
    float* st     = fp;                   fp += (size_t)N * DIM;
    float* agg    = fp;                   fp += (size_t)N * DIM;
    float* alr    = fp;                   fp += (size_t)N * 8;
    float* vl     = fp;                   fp += NF * F;
    float* vr     = fp;                   fp += NF * F;
    float* cc     = fp;                   fp += 4;
    float* pooled = fp;                   fp += G * DIM;
    float4* attp4 = (float4*)fp;          fp += (size_t)NF * E;
    int* ip    = (int*)fp;
    int* deg   = ip;                      ip += N;
    int* cnt   = ip;                      ip += N;   // deg & cnt adjacent -> one memset
    int* rowp  = ip;                      ip += N;
    int* bsum  = ip;                      ip += 256;
    int* gcnt  = ip;                      ip += G;
    int* goff  = ip;                      ip += G;
    int* esrc  = ip;                      ip += E;

    hipMemsetAsync(deg, 0, (size_t)(2 * N) * sizeof(int), stream);
    hipMemsetAsync(gcnt, 0, (size_t)G * sizeof(int), stream);

    prep_kernel<<<2, 256, 0, stream>>>(lin0_W, lin0_b, att_W, att_b, vl, vr, cc);
    encode_kernel<<<(N + 63) / 64, 256, 0, stream>>>(x, enc_W, enc_b, vl, vr, st, alr);
    att_kernel<<<(E + 255) / 256, 256, 0, stream>>>(ei, alr, cc, atts);

    // CSR build (once; reused by all 3 layers)
    hist_kernel<<<(E + 255) / 256, 256, 0, stream>>>(ei, deg);
    scan1_kernel<<<NB, 256, 0, stream>>>(deg, rowp, bsum);
    scan2_kernel<<<1, 256, 0, stream>>>(bsum);
    scan3_kernel<<<NB, 256, 0, stream>>>(rowp, bsum);
    fill_kernel<<<(E + 255) / 256, 256, 0, stream>>>(ei, atts, rowp, cnt, esrc, attp4);

    for (int l = 0; l < NL; ++l) {
        gather_kernel<<<N / 4, 256, 0, stream>>>(esrc, attp4, rowp, deg, st, agg);
        dim3 gupd((N + 63) / 64, NF);
        update_kernel<<<gupd, 64, 0, stream>>>(agg, st, conv_Wrel, conv_brel, conv_Wroot,
                                               gru_Wih, gru_Whh, gru_bih, gru_bhh, l);
    }

    ghist_kernel<<<(N + 255) / 256, 256, 0, stream>>>(batch, gcnt);
    gscan_kernel<<<1, 256, 0, stream>>>(gcnt, goff);
    pool_kernel<<<G, 256, 0, stream>>>(st, goff, gcnt, pooled, outsout);
    mlp_kernel<<<G, DIM, 0, stream>>>(pooled, fc1_W, fc1_b, fc2_W, fc2_b, pred);
}